// Round 13
// baseline (415.737 us; speedup 1.0000x reference)
//
#include <hip/hip_runtime.h>

typedef _Float16 h8  __attribute__((ext_vector_type(8)));
typedef float f32x16 __attribute__((ext_vector_type(16)));

#define L2E 1.4426950408889634f

__device__ __forceinline__ void gll16(const void* g, void* l) {
  __builtin_amdgcn_global_load_lds((const __attribute__((address_space(1))) void*)g,
                                   (__attribute__((address_space(3))) void*)l, 16, 0, 0);
}

// ---------------- kernel 0: x (f32) -> xh (f16) ----------------
__global__ void k_cvt_x(const float* __restrict__ x, _Float16* __restrict__ xh) {
  int i = (blockIdx.x * 256 + threadIdx.x) * 8;
  float4 a = *(const float4*)(x + i);
  float4 b = *(const float4*)(x + i + 4);
  h8 o;
  o[0] = (_Float16)a.x; o[1] = (_Float16)a.y; o[2] = (_Float16)a.z; o[3] = (_Float16)a.w;
  o[4] = (_Float16)b.x; o[5] = (_Float16)b.y; o[6] = (_Float16)b.z; o[7] = (_Float16)b.w;
  *(h8*)(xh + i) = o;
}

// ---------------- kernel 0b: W (1024x128 f32) -> WT (3x128x1024 f16) ------
__global__ void k_cvt_w(const float* __restrict__ Wq, const float* __restrict__ Wk,
                        const float* __restrict__ Wv, _Float16* __restrict__ WT) {
  int id = blockIdx.x * 256 + threadIdx.x;     // 0 .. 3*131072-1
  int mat = id >> 17;
  int rem = id & 131071;
  int k = rem >> 7;
  int c = rem & 127;
  const float* W = (mat == 0) ? Wq : ((mat == 1) ? Wk : Wv);
  WT[mat * 131072 + c * 1024 + k] = (_Float16)W[rem];
}

// ---------------- kernel 1: QKV projection + rotary + gate ----------------
// (unchanged; proven)
__global__ __launch_bounds__(256, 2) void k_proj(
    const _Float16* __restrict__ xh,   // [16384][1024]
    const _Float16* __restrict__ WT,   // [3][128][1024]
    const float* __restrict__ cosT, const float* __restrict__ sinT,  // [4096][64]
    const float* __restrict__ gamma,
    _Float16* __restrict__ Qh, _Float16* __restrict__ Kh, _Float16* __restrict__ VT) {
  __shared__ __align__(16) unsigned char lds[65536];  // [2 phase][x 16KB | w 16KB]
  const int tid = threadIdx.x;
  const int rt  = blockIdx.x & 127;
  const int mat = blockIdx.x >> 7;
  const int w = tid >> 6, lane = tid & 63;
  const int wr = w >> 1, wc = w & 1;
  const int r32 = lane & 31, h = lane >> 5;
  const int row0 = rt * 128;
  const _Float16* Wbase = WT + mat * 131072;

  auto stage = [&](int j) {
    int k0 = j * 64;
    unsigned char* xb = lds + (j & 1) * 32768;
    unsigned char* wb = xb + 16384;
#pragma unroll
    for (int ii = 0; ii < 4; ++ii) {
      int off = ii * 4096 + tid * 16;
      int r = off >> 7;            // row in tile (128B rows)
      int c = (off >> 4) & 7;      // 16B chunk slot
      gll16(xh + (size_t)(row0 + r) * 1024 + k0 + ((c ^ (r & 7)) * 8), xb + off);
    }
#pragma unroll
    for (int ii = 0; ii < 4; ++ii) {
      int off = ii * 4096 + tid * 16;
      int r = off >> 7;
      int c = (off >> 4) & 7;
      gll16(Wbase + (size_t)r * 1024 + k0 + ((c ^ (r & 7)) * 8), wb + off);
    }
  };

  f32x16 acc[2][2];
#pragma unroll
  for (int a_ = 0; a_ < 2; ++a_)
#pragma unroll
    for (int b_ = 0; b_ < 2; ++b_)
#pragma unroll
      for (int r = 0; r < 16; ++r) acc[a_][b_][r] = 0.f;

  stage(0);
  for (int j = 0; j < 16; ++j) {
    if (j < 15) {
      stage(j + 1);
      asm volatile("s_waitcnt vmcnt(8)\n\ts_barrier" ::: "memory");
    } else {
      asm volatile("s_waitcnt vmcnt(0)\n\ts_barrier" ::: "memory");
    }
    const _Float16* xt = (const _Float16*)(lds + (j & 1) * 32768);
    const _Float16* wt = xt + 8192;
#pragma unroll
    for (int kk = 0; kk < 4; ++kk) {
      h8 a0, a1, b0, b1;
      { int r = wr * 64 + r32;      a0 = *(const h8*)(xt + r * 64 + (((kk * 2 + h) ^ (r & 7)) * 8)); }
      { int r = wr * 64 + 32 + r32; a1 = *(const h8*)(xt + r * 64 + (((kk * 2 + h) ^ (r & 7)) * 8)); }
      { int r = wc * 64 + r32;      b0 = *(const h8*)(wt + r * 64 + (((kk * 2 + h) ^ (r & 7)) * 8)); }
      { int r = wc * 64 + 32 + r32; b1 = *(const h8*)(wt + r * 64 + (((kk * 2 + h) ^ (r & 7)) * 8)); }
      acc[0][0] = __builtin_amdgcn_mfma_f32_32x32x16_f16(a0, b0, acc[0][0], 0, 0, 0);
      acc[0][1] = __builtin_amdgcn_mfma_f32_32x32x16_f16(a0, b1, acc[0][1], 0, 0, 0);
      acc[1][0] = __builtin_amdgcn_mfma_f32_32x32x16_f16(a1, b0, acc[1][0], 0, 0, 0);
      acc[1][1] = __builtin_amdgcn_mfma_f32_32x32x16_f16(a1, b1, acc[1][1], 0, 0, 0);
    }
    asm volatile("s_waitcnt lgkmcnt(0)\n\ts_barrier" ::: "memory");
  }

#pragma unroll
  for (int mt = 0; mt < 2; ++mt)
#pragma unroll
    for (int nt = 0; nt < 2; ++nt) {
      int col = wc * 64 + nt * 32 + r32;
      f32x16 c = acc[mt][nt];
      if (mat < 2) {
        float ge = expf(gamma[col]);
        float sc = (mat == 0) ? ge * 0.08838834764831845f : ge;  // fold 1/sqrt(128) into Q
        int i2 = col >> 1;
#pragma unroll
        for (int rg = 0; rg < 16; ++rg) {
          int row = row0 + wr * 64 + mt * 32 + (rg & 3) + 8 * (rg >> 2) + 4 * h;
          int pos = row & 4095;
          float cv = cosT[pos * 64 + i2], sv = sinT[pos * 64 + i2];
          float val = c[rg];
          float ot = __shfl_xor(val, 1);
          // even d: t1*cos - t2*sin ; odd d: t1*sin + t2*cos
          float rr = (lane & 1) ? fmaf(val, cv, ot * sv) : fmaf(val, cv, -ot * sv);
          float v = rr * sc;
          if (mat == 0) {
            Qh[(size_t)row * 128 + col] = (_Float16)v;
          } else {
            size_t ka = (size_t)(row >> 5) * 4096 + (col >> 4) * 512 +
                        ((col >> 3) & 1) * 256 + (row & 31) * 8 + (col & 7);
            Kh[ka] = (_Float16)v;
          }
        }
      } else {
        // V fragment-major: rg group g covers 4 consecutive kv at fixed d=col.
#pragma unroll
        for (int g = 0; g < 4; ++g) {
          union { _Float16 hh[4]; uint2 u; } pk;
#pragma unroll
          for (int j2 = 0; j2 < 4; ++j2) pk.hh[j2] = (_Float16)c[g * 4 + j2];
          int kv = row0 + wr * 64 + mt * 32 + 8 * g + 4 * h;  // multiple of 4
          size_t va = (size_t)(kv >> 5) * 4096 +
                      ((col >> 5) * 2 + ((kv >> 4) & 1)) * 512 +
                      ((kv >> 3) & 1) * 256 + (col & 31) * 8 + (kv & 7);
          *(uint2*)(VT + va) = pk.u;
        }
      }
    }
}

// ---------------- kernel 2: flash attention (no-LDS loop, 4-wave blocks) ---
// grid = 1024 blocks x 256 thr = 4 waves: s = kv stream (0..3).
// Each block: one 32-row q-tile, HALF the KV (4 streams x 16 iters x 32 kv).
// 4 blocks/CU -> 16 waves/CU = 4 waves/SIMD (VGPR<=128 via (256,4); LDS 33KB).
// Partial (o,m,l) written to workspace; k_merge combines the two halves.
__global__ __launch_bounds__(256, 4) void k_attn(
    const _Float16* __restrict__ Qh, const _Float16* __restrict__ Kh,
    const _Float16* __restrict__ VT, float* __restrict__ po,
    float* __restrict__ pmA, float* __restrict__ plA) {
  __shared__ __align__(16) unsigned char smem[33792];  // MB 32KB (aliases OT) + ML 1KB
  const int tid = threadIdx.x;
  const int bid = blockIdx.x;
  const int xcd = bid & 7;
  const int b    = xcd >> 1;
  const int inner = bid >> 3;                  // 0..127
  const int qt   = (xcd & 1) * 64 + (inner >> 1);   // 0..127
  const int half = inner & 1;
  const int q0 = qt * 32;
  const int s = tid >> 6, lane = tid & 63;
  const int r32 = lane & 31, h = lane >> 5;

  // Q fragments in registers (B-operand of swapped QK^T)
  const _Float16* qrow = Qh + (size_t)(b * 4096 + q0 + r32) * 128;
  h8 qf[8];
#pragma unroll
  for (int kk = 0; kk < 8; ++kk) qf[kk] = *(const h8*)(qrow + kk * 16 + h * 8);

  // fragment bases: tiles t = b*128 + half*64 + 4*i + s, i in 0..15
  const size_t TSTRIDE = 4 * 4096;
  const _Float16* Kfb = Kh + (size_t)(b * 128 + half * 64 + s) * 4096 + lane * 8;
  const _Float16* Vfb = VT + (size_t)(b * 128 + half * 64 + s) * 4096 + lane * 8;

  f32x16 o_acc[4];
#pragma unroll
  for (int dt = 0; dt < 4; ++dt)
#pragma unroll
    for (int r = 0; r < 16; ++r) o_acc[dt][r] = 0.f;
  float mcur = -INFINITY, lsum = 0.f;

  // prologue: K(0) -> kf; st_cur = QK(0); kf <- K(1)
  h8 kf[8];
#pragma unroll
  for (int kk = 0; kk < 8; ++kk) kf[kk] = *(const h8*)(Kfb + kk * 512);
  f32x16 st_cur;
#pragma unroll
  for (int r = 0; r < 16; ++r) st_cur[r] = 0.f;
#pragma unroll
  for (int kk = 0; kk < 8; ++kk) {
    h8 a = kf[kk];
    kf[kk] = *(const h8*)(Kfb + TSTRIDE + kk * 512);
    st_cur = __builtin_amdgcn_mfma_f32_32x32x16_f16(a, qf[kk], st_cur, 0, 0, 0);
  }

  for (int i = 0; i < 16; ++i) {
    // V fragments for tile i (consumed by PV at end of iteration)
    const _Float16* Vcur = Vfb + (size_t)i * TSTRIDE;
    h8 vf[8];
#pragma unroll
    for (int u = 0; u < 8; ++u) vf[u] = *(const h8*)(Vcur + u * 512);

    // QK for tile i+1 (overlaps softmax below); refill kf for tile i+2
    f32x16 st_next;
#pragma unroll
    for (int r = 0; r < 16; ++r) st_next[r] = 0.f;
    if (i < 15) {
      const _Float16* Kn2 = Kfb + (size_t)(i + 2 < 16 ? i + 2 : 15) * TSTRIDE;
      __builtin_amdgcn_s_setprio(1);
#pragma unroll
      for (int kk = 0; kk < 8; ++kk) {
        h8 a = kf[kk];
        kf[kk] = *(const h8*)(Kn2 + kk * 512);
        st_next = __builtin_amdgcn_mfma_f32_32x32x16_f16(a, qf[kk], st_next, 0, 0, 0);
      }
      __builtin_amdgcn_s_setprio(0);
    }

    // online softmax on st_cur (per lane = one q row; partner half in lane^32)
    f32x16 st = st_cur;
    float pm = fmaxf(fmaxf(fmaxf(st[0], st[1]), fmaxf(st[2], st[3])),
                     fmaxf(fmaxf(st[4], st[5]), fmaxf(st[6], st[7])));
    float pm2 = fmaxf(fmaxf(fmaxf(st[8], st[9]), fmaxf(st[10], st[11])),
                      fmaxf(fmaxf(st[12], st[13]), fmaxf(st[14], st[15])));
    pm = fmaxf(pm, pm2);
    pm = fmaxf(pm, __shfl_xor(pm, 32));
    // defer-max: only rescale when the running max grew by > 8
    if (!__all(pm - mcur <= 8.0f)) {
      float mnew = fmaxf(mcur, pm);
      float fsc = exp2f((mcur - mnew) * L2E);
      lsum *= fsc;
#pragma unroll
      for (int dt = 0; dt < 4; ++dt) o_acc[dt] = o_acc[dt] * fsc;
      mcur = mnew;
    }
    float mn2 = mcur * L2E;
    float pv[16]; float ps = 0.f;
#pragma unroll
    for (int r = 0; r < 16; ++r) { pv[r] = exp2f(fmaf(st[r], L2E, -mn2)); ps += pv[r]; }
    ps += __shfl_xor(ps, 32);
    lsum += ps;

    // pack P to half2 words; kv pair of word t (own half h): 8*(t>>1) + 4h + 2*(t&1)
    unsigned int wrd[8], owd[8];
#pragma unroll
    for (int t8 = 0; t8 < 8; ++t8) {
      auto hp = __builtin_amdgcn_cvt_pkrtz(pv[2 * t8], pv[2 * t8 + 1]);
      wrd[t8] = __builtin_bit_cast(unsigned int, hp);
    }
#pragma unroll
    for (int t8 = 0; t8 < 8; ++t8) owd[t8] = (unsigned int)__shfl_xor((int)wrd[t8], 32);
    const bool hb = (h != 0);
    __builtin_amdgcn_s_setprio(1);
#pragma unroll
    for (int kvb = 0; kvb < 2; ++kvb) {
      union { unsigned int u[4]; h8 v; } pb;
      pb.u[0] = hb ? owd[4 * kvb + 2] : wrd[4 * kvb + 0];
      pb.u[1] = hb ? owd[4 * kvb + 3] : wrd[4 * kvb + 1];
      pb.u[2] = hb ? wrd[4 * kvb + 2] : owd[4 * kvb + 0];
      pb.u[3] = hb ? wrd[4 * kvb + 3] : owd[4 * kvb + 1];
#pragma unroll
      for (int dt = 0; dt < 4; ++dt)
        o_acc[dt] = __builtin_amdgcn_mfma_f32_32x32x16_f16(vf[dt * 2 + kvb], pb.v, o_acc[dt], 0, 0, 0);
    }
    __builtin_amdgcn_s_setprio(0);
    st_cur = st_next;
  }

  // ---- merge the 4 kv streams of this block ----
  float* MB = (float*)smem;                    // 2 slots x 4096 floats
  float* ML = (float*)(smem + 32768);          // [4 s][m 32 | l 32]
  if (lane < 32) {
    ML[s * 64 + lane] = mcur;
    ML[s * 64 + 32 + lane] = lsum;
  }
  __syncthreads();
  float msv[4], lsv[4];
  float m_blk = -INFINITY;
#pragma unroll
  for (int j = 0; j < 4; ++j) {
    msv[j] = ML[j * 64 + r32];
    lsv[j] = ML[j * 64 + 32 + r32];
    m_blk = fmaxf(m_blk, msv[j]);
  }
  float l_blk = 0.f;
#pragma unroll
  for (int j = 0; j < 4; ++j) l_blk += lsv[j] * exp2f((msv[j] - m_blk) * L2E);
  float fown = exp2f((msv[s] - m_blk) * L2E);
#pragma unroll
  for (int dt = 0; dt < 4; ++dt) o_acc[dt] = o_acc[dt] * fown;

  auto mbw = [&](int slot) {
    float* p = MB + slot * 4096;
#pragma unroll
    for (int dt = 0; dt < 4; ++dt)
#pragma unroll
      for (int rg = 0; rg < 16; ++rg) p[(dt * 16 + rg) * 64 + lane] = o_acc[dt][rg];
  };
  auto mba = [&](int slot) {
    float* p = MB + slot * 4096;
#pragma unroll
    for (int dt = 0; dt < 4; ++dt)
#pragma unroll
      for (int rg = 0; rg < 16; ++rg) o_acc[dt][rg] += p[(dt * 16 + rg) * 64 + lane];
  };
  if (s >= 2) mbw(s - 2);
  __syncthreads();
  if (s < 2) mba(s);
  __syncthreads();
  if (s == 1) mbw(0);
  __syncthreads();
  if (s == 0) mba(0);
  __syncthreads();

  // transpose (s==0 holds block partial) and store partial o, m, l
  const int growb = b * 4096 + q0;
  float* OT = (float*)smem;                    // [32 q][129], aliases MB
  if (s == 0) {
#pragma unroll
    for (int dt = 0; dt < 4; ++dt)
#pragma unroll
      for (int rg = 0; rg < 16; ++rg) {
        int d = dt * 32 + (rg & 3) + 8 * (rg >> 2) + 4 * h;
        OT[r32 * 129 + d] = o_acc[dt][rg];
      }
    if (lane < 32) {
      pmA[half * 16384 + growb + lane] = m_blk;
      plA[half * 16384 + growb + lane] = l_blk;
    }
  }
  __syncthreads();
#pragma unroll
  for (int p = 0; p < 4; ++p) {
    int idx = p * 256 + tid;                   // 0..1023
    int qr = idx >> 5, c4 = idx & 31;
    float4 v = *(const float4*)&OT[qr * 129 + c4 * 4];
    *(float4*)(po + ((size_t)half * 16384 + growb + qr) * 128 + c4 * 4) = v;
  }
}

// ---------------- kernel 3: merge the two kv-halves ----------------
__global__ __launch_bounds__(256) void k_merge(
    const float* __restrict__ po, const float* __restrict__ pmA,
    const float* __restrict__ plA, float* __restrict__ out) {
  const int tid = threadIdx.x;
  const int r0 = blockIdx.x * 32;
#pragma unroll
  for (int p = 0; p < 4; ++p) {
    int idx = p * 256 + tid;
    int row = r0 + (idx >> 5);
    int c4 = idx & 31;
    float m0 = pmA[row], m1 = pmA[16384 + row];
    float l0 = plA[row], l1 = plA[16384 + row];
    float ms = fmaxf(m0, m1);
    float f0 = exp2f((m0 - ms) * L2E), f1 = exp2f((m1 - ms) * L2E);
    float inv = 1.0f / fmaf(l0, f0, l1 * f1);
    float4 a = *(const float4*)(po + (size_t)row * 128 + c4 * 4);
    float4 b = *(const float4*)(po + (size_t)(16384 + row) * 128 + c4 * 4);
    float4 o;
    o.x = fmaf(a.x, f0, b.x * f1) * inv;
    o.y = fmaf(a.y, f0, b.y * f1) * inv;
    o.z = fmaf(a.z, f0, b.z * f1) * inv;
    o.w = fmaf(a.w, f0, b.w * f1) * inv;
    *(float4*)(out + (size_t)row * 128 + c4 * 4) = o;
  }
}

// ---------------- launcher ----------------
extern "C" void kernel_launch(void* const* d_in, const int* in_sizes, int n_in,
                              void* d_out, int out_size, void* d_ws, size_t ws_size,
                              hipStream_t stream) {
  const float* x     = (const float*)d_in[0];
  const float* cosT  = (const float*)d_in[1];
  const float* sinT  = (const float*)d_in[2];
  const float* Wq    = (const float*)d_in[3];
  const float* Wk    = (const float*)d_in[4];
  const float* Wv    = (const float*)d_in[5];
  const float* gamma = (const float*)d_in[6];
  char* ws = (char*)d_ws;
  _Float16* xh = (_Float16*)(ws);                    // 33,554,432 B (dead after k_proj)
  _Float16* WT = (_Float16*)(ws + 33554432);         //    786,432 B
  _Float16* Qh = (_Float16*)(ws + 34340864);         //  4,194,304 B
  _Float16* Kh = (_Float16*)(ws + 38535168);         //  4,194,304 B (fragment-major)
  _Float16* VT = (_Float16*)(ws + 42729472);         //  4,194,304 B (fragment-major)
  // partials overlay the xh region (k_attn runs after k_proj):
  float* po  = (float*)(ws);                         // 2 x 16384 x 128 f32 = 16,777,216 B
  float* pmA = (float*)(ws + 16777216);              // 2 x 16384 f32 = 131,072 B
  float* plA = (float*)(ws + 16908288);              // 2 x 16384 f32 = 131,072 B
  float* out = (float*)d_out;

  hipLaunchKernelGGL(k_cvt_x, dim3(8192), dim3(256), 0, stream, x, xh);
  hipLaunchKernelGGL(k_cvt_w, dim3(1536), dim3(256), 0, stream, Wq, Wk, Wv, WT);
  hipLaunchKernelGGL(k_proj, dim3(384), dim3(256), 0, stream, xh, WT, cosT, sinT, gamma, Qh, Kh, VT);
  hipLaunchKernelGGL(k_attn, dim3(1024), dim3(256), 0, stream, Qh, Kh, VT, po, pmA, plA);
  hipLaunchKernelGGL(k_merge, dim3(512), dim3(256), 0, stream, po, pmA, plA, out);
}